// Round 1
// baseline (68.510 us; speedup 1.0000x reference)
//
#include <hip/hip_runtime.h>

#define L2E 1.44269504088896340736f
#define CSC 2.88539008177792681f  // 2*log2(e)

__device__ __forceinline__ float fast_exp2(float x) {
#if __has_builtin(__builtin_amdgcn_exp2f)
  return __builtin_amdgcn_exp2f(x);
#else
  return exp2f(x);
#endif
}
__device__ __forceinline__ float fast_rcp(float x) {
#if __has_builtin(__builtin_amdgcn_rcpf)
  return __builtin_amdgcn_rcpf(x);
#else
  return 1.0f / x;
#endif
}

// Projection: 256 blocks x 256 threads. Blocks 0..127 -> query rows (Eq),
// 128..255 -> key rows (Ek). Each block: 16 rows.
// dst[r][e] = exp2(CSC * sum_d src[r][d] * weight[e][woff+d])
__global__ __launch_bounds__(256) void proj_kernel(
    const float* __restrict__ query, const float* __restrict__ key,
    const float* __restrict__ weight, float* __restrict__ Eq,
    float* __restrict__ Ek) {
  __shared__ __align__(16) float rows[16][128];
  int blk = blockIdx.x;
  bool isK = blk >= 128;
  const float* src = isK ? key : query;
  float* dst = isK ? Ek : Eq;
  int woff = isK ? 128 : 0;
  int row0 = (isK ? blk - 128 : blk) * 16;
  int tid = threadIdx.x;
#pragma unroll
  for (int i = 0; i < 8; ++i) {
    int f = i * 256 + tid;
    rows[f >> 7][f & 127] = src[(size_t)row0 * 128 + f];
  }
  __syncthreads();
  int e = tid & 127;
  int rh = (tid >> 7) * 8;  // wave-uniform
  float acc[8];
#pragma unroll
  for (int i = 0; i < 8; ++i) acc[i] = 0.f;
  const float4* wrow =
      reinterpret_cast<const float4*>(weight + (size_t)e * 256 + woff);
#pragma unroll 4
  for (int d4 = 0; d4 < 32; ++d4) {
    float4 wv = wrow[d4];
#pragma unroll
    for (int i = 0; i < 8; ++i) {
      float4 rv = *reinterpret_cast<const float4*>(&rows[rh + i][d4 * 4]);
      acc[i] = fmaf(rv.x, wv.x, acc[i]);
      acc[i] = fmaf(rv.y, wv.y, acc[i]);
      acc[i] = fmaf(rv.z, wv.z, acc[i]);
      acc[i] = fmaf(rv.w, wv.w, acc[i]);
    }
  }
#pragma unroll
  for (int i = 0; i < 8; ++i)
    dst[(size_t)(row0 + rh + i) * 128 + e] = fast_exp2(CSC * acc[i]);
}

// Attention: 512 blocks (b = blk>>8, q0 = (blk&255)*4) x 256 threads (4 waves).
// Block owns 4 q-rows and all 1024 k. Wave w covers k-slice; lane -> k.
// score = SV - 2 * sum_e vT[e] / (1 + Eq[q][e]*Ek[k][e])   (== sum vT*tanh)
__global__ __launch_bounds__(256) void attn_kernel(
    const float* __restrict__ Eq, const float* __restrict__ Ek,
    const float* __restrict__ vT, const float* __restrict__ value,
    float* __restrict__ out) {
  __shared__ __align__(16) float sc[4][1024];
  __shared__ __align__(16) float eq_lds[4][128];
  __shared__ __align__(16) float vt_lds[128];
  __shared__ float2 pout[4][4][64];
  __shared__ float denomLds[4];

  int tid = threadIdx.x;
  int lane = tid & 63;
  int w = tid >> 6;
  int b = blockIdx.x >> 8;
  int q0 = (blockIdx.x & 255) * 4;

  for (int i = tid; i < 512; i += 256)
    eq_lds[i >> 7][i & 127] =
        Eq[((size_t)(b * 1024 + q0) + (i >> 7)) * 128 + (i & 127)];
  if (tid < 128) vt_lds[tid] = vT[tid];
  __syncthreads();

  float SV = 0.f;
#pragma unroll 16
  for (int e2 = 0; e2 < 128; ++e2) SV += vt_lds[e2];

  // ---- scores ----
  for (int kt = 0; kt < 4; ++kt) {
    int k = kt * 256 + w * 64 + lane;
    const float4* ekrow =
        reinterpret_cast<const float4*>(Ek + ((size_t)b * 1024 + k) * 128);
    float acc[4] = {0.f, 0.f, 0.f, 0.f};
#pragma unroll 2
    for (int ec = 0; ec < 8; ++ec) {
      float4 ekv[4], vtv[4];
#pragma unroll
      for (int j = 0; j < 4; ++j) ekv[j] = ekrow[ec * 4 + j];
#pragma unroll
      for (int j = 0; j < 4; ++j)
        vtv[j] = *reinterpret_cast<const float4*>(&vt_lds[ec * 16 + j * 4]);
#pragma unroll
      for (int qi = 0; qi < 4; ++qi) {
#pragma unroll
        for (int j = 0; j < 4; ++j) {
          float4 eqv =
              *reinterpret_cast<const float4*>(&eq_lds[qi][ec * 16 + j * 4]);
          acc[qi] += vtv[j].x * fast_rcp(fmaf(eqv.x, ekv[j].x, 1.f));
          acc[qi] += vtv[j].y * fast_rcp(fmaf(eqv.y, ekv[j].y, 1.f));
          acc[qi] += vtv[j].z * fast_rcp(fmaf(eqv.z, ekv[j].z, 1.f));
          acc[qi] += vtv[j].w * fast_rcp(fmaf(eqv.w, ekv[j].w, 1.f));
        }
      }
    }
#pragma unroll
    for (int qi = 0; qi < 4; ++qi) sc[qi][k] = fmaf(-2.f, acc[qi], SV);
  }
  __syncthreads();

  // ---- softmax: wave w handles q-row w ----
  {
    float sv[16];
    float m = -3.0e38f;
#pragma unroll
    for (int i = 0; i < 16; ++i) {
      sv[i] = sc[w][i * 64 + lane];
      m = fmaxf(m, sv[i]);
    }
#pragma unroll
    for (int off = 32; off; off >>= 1) m = fmaxf(m, __shfl_xor(m, off));
    float sum = 0.f;
#pragma unroll
    for (int i = 0; i < 16; ++i) {
      float p = fast_exp2((sv[i] - m) * L2E);
      sc[w][i * 64 + lane] = p;
      sum += p;
    }
#pragma unroll
    for (int off = 32; off; off >>= 1) sum += __shfl_xor(sum, off);
    if (lane == 0) denomLds[w] = sum;
  }
  __syncthreads();

  // ---- PV: wave w sums k in [w*256, w*256+256), lanes -> v (float2) ----
  float2 acc2[4];
#pragma unroll
  for (int qi = 0; qi < 4; ++qi) acc2[qi] = make_float2(0.f, 0.f);
  const float2* v2p =
      reinterpret_cast<const float2*>(value) + (size_t)b * 1024 * 64;
  for (int i = 0; i < 256; ++i) {
    int k = w * 256 + i;
    float2 vv = v2p[(size_t)k * 64 + lane];
#pragma unroll
    for (int qi = 0; qi < 4; ++qi) {
      float p = sc[qi][k];
      acc2[qi].x = fmaf(p, vv.x, acc2[qi].x);
      acc2[qi].y = fmaf(p, vv.y, acc2[qi].y);
    }
  }
#pragma unroll
  for (int qi = 0; qi < 4; ++qi) pout[w][qi][lane] = acc2[qi];
  __syncthreads();
  {
    int qi = tid >> 6;
    float2 r = pout[0][qi][lane];
#pragma unroll
    for (int ww = 1; ww < 4; ++ww) {
      r.x += pout[ww][qi][lane].x;
      r.y += pout[ww][qi][lane].y;
    }
    float inv = fast_rcp(denomLds[qi]);
    r.x *= inv;
    r.y *= inv;
    reinterpret_cast<float2*>(out)[((size_t)b * 1024 + q0 + qi) * 64 + lane] = r;
  }
}

extern "C" void kernel_launch(void* const* d_in, const int* in_sizes, int n_in,
                              void* d_out, int out_size, void* d_ws,
                              size_t ws_size, hipStream_t stream) {
  const float* query = (const float*)d_in[0];
  const float* key = (const float*)d_in[1];
  const float* value = (const float*)d_in[2];
  const float* vT = (const float*)d_in[3];
  const float* weight = (const float*)d_in[4];
  float* out = (float*)d_out;
  float* Eq = (float*)d_ws;           // 2048*128 f32 = 1 MB
  float* Ek = Eq + 2048 * 128;        // 1 MB
  proj_kernel<<<256, 256, 0, stream>>>(query, key, weight, Eq, Ek);
  attn_kernel<<<512, 256, 0, stream>>>(Eq, Ek, vT, value, out);
}

// Round 2
// 61.097 us; speedup vs baseline: 1.1213x; 1.1213x over previous
//
#include <hip/hip_runtime.h>

#define L2E 1.44269504088896340736f
#define CSC 2.88539008177792681f  // 2*log2(e)

__device__ __forceinline__ float fast_exp2(float x) {
  return __builtin_amdgcn_exp2f(x);
}
__device__ __forceinline__ float fast_rcp(float x) {
  return __builtin_amdgcn_rcpf(x);
}

// Projection: 256 blocks x 256 threads. Blocks 0..127 -> query rows (Eq),
// 128..255 -> key rows (Ek). Each block: 16 rows.
// dst[r][e] = exp2(CSC * sum_d src[r][d] * weight[e][woff+d])
__global__ __launch_bounds__(256) void proj_kernel(
    const float* __restrict__ query, const float* __restrict__ key,
    const float* __restrict__ weight, float* __restrict__ Eq,
    float* __restrict__ Ek) {
  __shared__ __align__(16) float rows[16][128];
  int blk = blockIdx.x;
  bool isK = blk >= 128;
  const float* src = isK ? key : query;
  float* dst = isK ? Ek : Eq;
  int woff = isK ? 128 : 0;
  int row0 = (isK ? blk - 128 : blk) * 16;
  int tid = threadIdx.x;
#pragma unroll
  for (int i = 0; i < 8; ++i) {
    int f = i * 256 + tid;
    rows[f >> 7][f & 127] = src[(size_t)row0 * 128 + f];
  }
  __syncthreads();
  int e = tid & 127;
  int rh = (tid >> 7) * 8;  // wave-uniform
  float acc[8];
#pragma unroll
  for (int i = 0; i < 8; ++i) acc[i] = 0.f;
  const float4* wrow =
      reinterpret_cast<const float4*>(weight + (size_t)e * 256 + woff);
#pragma unroll 4
  for (int d4 = 0; d4 < 32; ++d4) {
    float4 wv = wrow[d4];
#pragma unroll
    for (int i = 0; i < 8; ++i) {
      float4 rv = *reinterpret_cast<const float4*>(&rows[rh + i][d4 * 4]);
      acc[i] = fmaf(rv.x, wv.x, acc[i]);
      acc[i] = fmaf(rv.y, wv.y, acc[i]);
      acc[i] = fmaf(rv.z, wv.z, acc[i]);
      acc[i] = fmaf(rv.w, wv.w, acc[i]);
    }
  }
#pragma unroll
  for (int i = 0; i < 8; ++i)
    dst[(size_t)(row0 + rh + i) * 128 + e] = fast_exp2(CSC * acc[i]);
}

// 4-way reciprocal combine:
//   sum_i v_i/(1+a_i)  with A_i = 1+eq_i*ek_i
//   = [ (v0*A1+v1*A0)*A2*A3 + (v2*A3+v3*A2)*A0*A1 ] / (A0*A1*A2*A3)
// 14 full-rate VALU + 1 rcp per 4 elements.
#define QUAD(EQ, EK, VT, ACC)                          \
  {                                                    \
    float A0 = fmaf((EQ).x, (EK).x, 1.f);              \
    float A1 = fmaf((EQ).y, (EK).y, 1.f);              \
    float A2 = fmaf((EQ).z, (EK).z, 1.f);              \
    float A3 = fmaf((EQ).w, (EK).w, 1.f);              \
    float P01 = A0 * A1;                               \
    float P23 = A2 * A3;                               \
    float t01 = fmaf((VT).x, A1, (VT).y * A0);         \
    float t23 = fmaf((VT).z, A3, (VT).w * A2);         \
    float num = fmaf(t23, P01, t01 * P23);             \
    float den = P01 * P23;                             \
    (ACC) = fmaf(num, fast_rcp(den), (ACC));           \
  }

// Attention: 512 blocks (b = blk>>8, q0 = (blk&255)*4) x 512 threads (8 waves)
// Block owns 4 q-rows and all 1024 k. score' = -2 * sum_e vT_e/(1+Eq*Ek)
// (the constant sum(vT) term cancels in softmax; scores bounded so no max
// subtraction needed: |score'| <= 2*sum|vT| ~ 18, exp2 arg <= ~27, f32-safe)
__global__ __launch_bounds__(512, 4) void attn_kernel(
    const float* __restrict__ Eq, const float* __restrict__ Ek,
    const float* __restrict__ vT, const float* __restrict__ value,
    float* __restrict__ out) {
  __shared__ __align__(16) float sc[4][1024];
  __shared__ __align__(16) float eq_lds[4][128];
  __shared__ __align__(16) float vt_lds[128];
  __shared__ float2 pout[8][4][64];
  __shared__ float denom[4];
  __shared__ float wsum[8];

  int tid = threadIdx.x;
  int lane = tid & 63;
  int w = tid >> 6;
  int b = blockIdx.x >> 8;
  int q0 = (blockIdx.x & 255) * 4;

  eq_lds[tid >> 7][tid & 127] =
      Eq[((size_t)(b * 1024 + q0) + (tid >> 7)) * 128 + (tid & 127)];
  if (tid < 128) vt_lds[tid] = vT[tid];
  __syncthreads();

  // ---- scores: thread covers k = tid and k = 512 + tid ----
  const float* ekr0 = Ek + ((size_t)b * 1024 + tid) * 128;
  const float* ekr1 = ekr0 + (size_t)512 * 128;
  float acc[4][2];
#pragma unroll
  for (int qi = 0; qi < 4; ++qi) {
    acc[qi][0] = 0.f;
    acc[qi][1] = 0.f;
  }
#pragma unroll 2
  for (int ec = 0; ec < 16; ++ec) {  // 8 e per chunk
    float4 eqv[4][2];
    float4 vtv[2];
#pragma unroll
    for (int j = 0; j < 2; ++j)
      vtv[j] = *reinterpret_cast<const float4*>(&vt_lds[ec * 8 + j * 4]);
#pragma unroll
    for (int qi = 0; qi < 4; ++qi)
#pragma unroll
      for (int j = 0; j < 2; ++j)
        eqv[qi][j] =
            *reinterpret_cast<const float4*>(&eq_lds[qi][ec * 8 + j * 4]);
#pragma unroll
    for (int kt = 0; kt < 2; ++kt) {
      const float* ekp = kt ? ekr1 : ekr0;
      float4 ekv[2];
      ekv[0] = *reinterpret_cast<const float4*>(ekp + ec * 8);
      ekv[1] = *reinterpret_cast<const float4*>(ekp + ec * 8 + 4);
#pragma unroll
      for (int qi = 0; qi < 4; ++qi) {
        QUAD(eqv[qi][0], ekv[0], vtv[0], acc[qi][kt]);
        QUAD(eqv[qi][1], ekv[1], vtv[1], acc[qi][kt]);
      }
    }
  }
#pragma unroll
  for (int qi = 0; qi < 4; ++qi) {
    sc[qi][tid] = acc[qi][0];
    sc[qi][512 + tid] = acc[qi][1];
  }
  __syncthreads();

  // ---- softmax (no max pass): wave w -> row w>>1, half w&1 ----
  {
    int r = w >> 1, h = w & 1;
    float sum = 0.f;
#pragma unroll
    for (int i = 0; i < 8; ++i) {
      int k = h * 512 + i * 64 + lane;
      float p = fast_exp2(-CSC * sc[r][k]);
      sc[r][k] = p;
      sum += p;
    }
#pragma unroll
    for (int off = 32; off; off >>= 1) sum += __shfl_xor(sum, off);
    if (lane == 0) wsum[w] = sum;
  }
  __syncthreads();
  if (tid < 4) denom[tid] = wsum[2 * tid] + wsum[2 * tid + 1];

  // ---- PV: wave w sums k in [w*128, w*128+128), lanes -> v (float2) ----
  float2 a2[4];
#pragma unroll
  for (int qi = 0; qi < 4; ++qi) a2[qi] = make_float2(0.f, 0.f);
  const float2* v2p =
      reinterpret_cast<const float2*>(value) + (size_t)b * 1024 * 64;
  int kbase = w * 128;
#pragma unroll 2
  for (int i = 0; i < 128; ++i) {
    int k = kbase + i;
    float2 vv = v2p[(size_t)k * 64 + lane];
#pragma unroll
    for (int qi = 0; qi < 4; ++qi) {
      float p = sc[qi][k];
      a2[qi].x = fmaf(p, vv.x, a2[qi].x);
      a2[qi].y = fmaf(p, vv.y, a2[qi].y);
    }
  }
#pragma unroll
  for (int qi = 0; qi < 4; ++qi) pout[w][qi][lane] = a2[qi];
  __syncthreads();
  if (tid < 256) {
    int qi = tid >> 6;
    float2 r = pout[0][qi][lane];
#pragma unroll
    for (int ww = 1; ww < 8; ++ww) {
      r.x += pout[ww][qi][lane].x;
      r.y += pout[ww][qi][lane].y;
    }
    float inv = fast_rcp(denom[qi]);
    r.x *= inv;
    r.y *= inv;
    reinterpret_cast<float2*>(out)[((size_t)b * 1024 + q0 + qi) * 64 + lane] =
        r;
  }
}

extern "C" void kernel_launch(void* const* d_in, const int* in_sizes, int n_in,
                              void* d_out, int out_size, void* d_ws,
                              size_t ws_size, hipStream_t stream) {
  const float* query = (const float*)d_in[0];
  const float* key = (const float*)d_in[1];
  const float* value = (const float*)d_in[2];
  const float* vT = (const float*)d_in[3];
  const float* weight = (const float*)d_in[4];
  float* out = (float*)d_out;
  float* Eq = (float*)d_ws;     // 2048*128 f32 = 1 MB
  float* Ek = Eq + 2048 * 128;  // 1 MB
  proj_kernel<<<256, 256, 0, stream>>>(query, key, weight, Eq, Ek);
  attn_kernel<<<512, 512, 0, stream>>>(Eq, Ek, vT, value, out);
}

// Round 3
// 49.824 us; speedup vs baseline: 1.3750x; 1.2263x over previous
//
#include <hip/hip_runtime.h>

#define L2E 1.44269504088896340736f
#define CSC 2.88539008177792681f  // 2*log2(e)

__device__ __forceinline__ float fast_exp2(float x) {
  return __builtin_amdgcn_exp2f(x);
}
__device__ __forceinline__ float fast_rcp(float x) {
  return __builtin_amdgcn_rcpf(x);
}

__device__ __forceinline__ float4 f4_a(float s, const float4& b) {  // 1+s*b
  return make_float4(fmaf(s, b.x, 1.f), fmaf(s, b.y, 1.f), fmaf(s, b.z, 1.f),
                     fmaf(s, b.w, 1.f));
}
__device__ __forceinline__ float4 f4_fma_s(float a, const float4& b,
                                           const float4& c) {
  return make_float4(fmaf(a, b.x, c.x), fmaf(a, b.y, c.y), fmaf(a, b.z, c.z),
                     fmaf(a, b.w, c.w));
}
__device__ __forceinline__ float4 f4_mul_s(float a, const float4& b) {
  return make_float4(a * b.x, a * b.y, a * b.z, a * b.w);
}
__device__ __forceinline__ float4 f4_mul(const float4& a, const float4& b) {
  return make_float4(a.x * b.x, a.y * b.y, a.z * b.z, a.w * b.w);
}
__device__ __forceinline__ float4 f4_fma(const float4& a, const float4& b,
                                         const float4& c) {
  return make_float4(fmaf(a.x, b.x, c.x), fmaf(a.y, b.y, c.y),
                     fmaf(a.z, b.z, c.z), fmaf(a.w, b.w, c.w));
}
__device__ __forceinline__ float4 f4_add(const float4& a, const float4& b) {
  return make_float4(a.x + b.x, a.y + b.y, a.z + b.z, a.w + b.w);
}
__device__ __forceinline__ float4 f4_rcp(const float4& a) {
  return make_float4(fast_rcp(a.x), fast_rcp(a.y), fast_rcp(a.z),
                     fast_rcp(a.w));
}

// 4-way reciprocal combine over an e-quad, float4-wide over 4 k:
//   sum_e vT_e/(1+eq_e*ek_e[k]) = num/den  (all A_i >= 1, f32-safe: den<=2^80)
#define QUAD4(EQ, VT, EK0, EK1, EK2, EK3, ACC)               \
  {                                                          \
    float4 A0 = f4_a((EQ).x, EK0);                           \
    float4 A1 = f4_a((EQ).y, EK1);                           \
    float4 A2 = f4_a((EQ).z, EK2);                           \
    float4 A3 = f4_a((EQ).w, EK3);                           \
    float4 P01 = f4_mul(A0, A1);                             \
    float4 P23 = f4_mul(A2, A3);                             \
    float4 t01 = f4_fma_s((VT).x, A1, f4_mul_s((VT).y, A0)); \
    float4 t23 = f4_fma_s((VT).z, A3, f4_mul_s((VT).w, A2)); \
    float4 num = f4_fma(t23, P01, f4_mul(t01, P23));         \
    float4 den = f4_mul(P01, P23);                           \
    (ACC) = f4_fma(num, f4_rcp(den), (ACC));                 \
  }

// Projection: 256 blocks x 256 threads. Blocks 0..127 -> Eq (row-major
// [qrow][e]); 128..255 -> EkT TRANSPOSED ([e][2048] where col = b*1024+k) so
// the attention score loop reads Ek coalesced over k.
__global__ __launch_bounds__(256) void proj_kernel(
    const float* __restrict__ query, const float* __restrict__ key,
    const float* __restrict__ weight, float* __restrict__ Eq,
    float* __restrict__ EkT) {
  __shared__ __align__(16) float rows[16][128];
  __shared__ __align__(16) float tile[16][128];
  int blk = blockIdx.x;
  bool isK = blk >= 128;
  const float* src = isK ? key : query;
  int woff = isK ? 128 : 0;
  int row0 = (isK ? blk - 128 : blk) * 16;
  int tid = threadIdx.x;
#pragma unroll
  for (int i = 0; i < 8; ++i) {
    int f = i * 256 + tid;
    rows[f >> 7][f & 127] = src[(size_t)row0 * 128 + f];
  }
  __syncthreads();
  int e = tid & 127;
  int rh = (tid >> 7) * 8;  // wave-uniform
  float acc[8];
#pragma unroll
  for (int i = 0; i < 8; ++i) acc[i] = 0.f;
  const float4* wrow =
      reinterpret_cast<const float4*>(weight + (size_t)e * 256 + woff);
#pragma unroll 4
  for (int d4 = 0; d4 < 32; ++d4) {
    float4 wv = wrow[d4];
#pragma unroll
    for (int i = 0; i < 8; ++i) {
      float4 rv = *reinterpret_cast<const float4*>(&rows[rh + i][d4 * 4]);
      acc[i] = fmaf(rv.x, wv.x, acc[i]);
      acc[i] = fmaf(rv.y, wv.y, acc[i]);
      acc[i] = fmaf(rv.z, wv.z, acc[i]);
      acc[i] = fmaf(rv.w, wv.w, acc[i]);
    }
  }
  if (!isK) {
#pragma unroll
    for (int i = 0; i < 8; ++i)
      Eq[(size_t)(row0 + rh + i) * 128 + e] = fast_exp2(CSC * acc[i]);
  } else {
#pragma unroll
    for (int i = 0; i < 8; ++i) tile[rh + i][e] = fast_exp2(CSC * acc[i]);
    __syncthreads();
    int eo = tid >> 1;
    int rseg = (tid & 1) * 8;
    float4 v0 = make_float4(tile[rseg + 0][eo], tile[rseg + 1][eo],
                            tile[rseg + 2][eo], tile[rseg + 3][eo]);
    float4 v1 = make_float4(tile[rseg + 4][eo], tile[rseg + 5][eo],
                            tile[rseg + 6][eo], tile[rseg + 7][eo]);
    float* dst = EkT + (size_t)eo * 2048 + row0 + rseg;
    *reinterpret_cast<float4*>(dst) = v0;
    *reinterpret_cast<float4*>(dst + 4) = v1;
  }
}

// Attention: 512 blocks (b = blk>>8, q0 = (blk&255)*4) x 512 threads (8 waves)
// Score phase: thread -> 4 consecutive k (float4 lane-vectorized, coalesced
// EkT reads) x 2 q rows. score' = -2 * sum_e vT_e/(1+Eq*Ek); sum(vT) const
// cancels in softmax; |score'| <= ~18 so no max-subtraction needed.
__global__ __launch_bounds__(512, 4) void attn_kernel(
    const float* __restrict__ Eq, const float* __restrict__ EkT,
    const float* __restrict__ vT, const float* __restrict__ value,
    float* __restrict__ out) {
  __shared__ __align__(16) float sc[4][1024];
  __shared__ __align__(16) float eq_lds[4][128];
  __shared__ __align__(16) float vt_lds[128];
  __shared__ __align__(16) float4 pout[8][4][32];
  __shared__ float denom[4];
  __shared__ float wsum[8];

  int tid = threadIdx.x;
  int lane = tid & 63;
  int w = tid >> 6;
  int b = blockIdx.x >> 8;
  int q0 = (blockIdx.x & 255) * 4;

  eq_lds[tid >> 7][tid & 127] =
      Eq[((size_t)(b * 1024 + q0) + (tid >> 7)) * 128 + (tid & 127)];
  if (tid < 128) vt_lds[tid] = vT[tid];
  __syncthreads();

  // ---- scores ----
  {
    int kg = tid & 255;        // k-group (4 consecutive k)
    int qh = (tid >> 8) * 2;   // first q row (wave-uniform)
    const float* ekp = EkT + (size_t)b * 1024 + kg * 4;
    float4 acc0 = make_float4(0.f, 0.f, 0.f, 0.f);
    float4 acc1 = make_float4(0.f, 0.f, 0.f, 0.f);
#pragma unroll 2
    for (int e = 0; e < 128; e += 4) {
      float4 ek0 = *reinterpret_cast<const float4*>(ekp + (size_t)(e + 0) * 2048);
      float4 ek1 = *reinterpret_cast<const float4*>(ekp + (size_t)(e + 1) * 2048);
      float4 ek2 = *reinterpret_cast<const float4*>(ekp + (size_t)(e + 2) * 2048);
      float4 ek3 = *reinterpret_cast<const float4*>(ekp + (size_t)(e + 3) * 2048);
      float4 vt4 = *reinterpret_cast<const float4*>(&vt_lds[e]);
      float4 eqA = *reinterpret_cast<const float4*>(&eq_lds[qh][e]);
      float4 eqB = *reinterpret_cast<const float4*>(&eq_lds[qh + 1][e]);
      QUAD4(eqA, vt4, ek0, ek1, ek2, ek3, acc0);
      QUAD4(eqB, vt4, ek0, ek1, ek2, ek3, acc1);
    }
    *reinterpret_cast<float4*>(&sc[qh][kg * 4]) = acc0;
    *reinterpret_cast<float4*>(&sc[qh + 1][kg * 4]) = acc1;
  }
  __syncthreads();

  // ---- softmax (no max pass): wave w -> row w>>1, half w&1 ----
  {
    int r = w >> 1, h = w & 1;
    float sum = 0.f;
#pragma unroll
    for (int i = 0; i < 8; ++i) {
      int k = h * 512 + i * 64 + lane;
      float p = fast_exp2(-CSC * sc[r][k]);
      sc[r][k] = p;
      sum += p;
    }
#pragma unroll
    for (int off = 32; off; off >>= 1) sum += __shfl_xor(sum, off);
    if (lane == 0) wsum[w] = sum;
  }
  __syncthreads();
  if (tid < 4) denom[tid] = wsum[2 * tid] + wsum[2 * tid + 1];

  // ---- PV: wave w -> k in [w*128, w*128+128); lane: kpar = lane>>5,
  //      c = lane&31 (float4 over v). Coalesced 1KB value loads. ----
  {
    float4 a4[4];
#pragma unroll
    for (int qi = 0; qi < 4; ++qi) a4[qi] = make_float4(0.f, 0.f, 0.f, 0.f);
    const float4* v4p =
        reinterpret_cast<const float4*>(value) + (size_t)b * 1024 * 32;
    int c = lane & 31;
    int kpar = lane >> 5;
    int kbase = w * 128;
#pragma unroll 2
    for (int i = 0; i < 64; ++i) {
      int k = kbase + i * 2 + kpar;
      float4 vv = v4p[(size_t)k * 32 + c];
#pragma unroll
      for (int qi = 0; qi < 4; ++qi) a4[qi] = f4_fma_s(sc[qi][k], vv, a4[qi]);
    }
#pragma unroll
    for (int qi = 0; qi < 4; ++qi) {
      a4[qi].x += __shfl_xor(a4[qi].x, 32);
      a4[qi].y += __shfl_xor(a4[qi].y, 32);
      a4[qi].z += __shfl_xor(a4[qi].z, 32);
      a4[qi].w += __shfl_xor(a4[qi].w, 32);
    }
    if (lane < 32) {
#pragma unroll
      for (int qi = 0; qi < 4; ++qi) pout[w][qi][c] = a4[qi];
    }
  }
  __syncthreads();
  if (tid < 128) {
    int qi = tid >> 5, c2 = tid & 31;
    float4 r = pout[0][qi][c2];
#pragma unroll
    for (int ww = 1; ww < 8; ++ww) r = f4_add(r, pout[ww][qi][c2]);
    float inv = fast_rcp(denom[qi]);
    r.x *= inv;
    r.y *= inv;
    r.z *= inv;
    r.w *= inv;
    reinterpret_cast<float4*>(out)[((size_t)b * 1024 + q0 + qi) * 32 + c2] = r;
  }
}

extern "C" void kernel_launch(void* const* d_in, const int* in_sizes, int n_in,
                              void* d_out, int out_size, void* d_ws,
                              size_t ws_size, hipStream_t stream) {
  const float* query = (const float*)d_in[0];
  const float* key = (const float*)d_in[1];
  const float* value = (const float*)d_in[2];
  const float* vT = (const float*)d_in[3];
  const float* weight = (const float*)d_in[4];
  float* out = (float*)d_out;
  float* Eq = (float*)d_ws;      // 2048*128 f32 = 1 MB
  float* EkT = Eq + 2048 * 128;  // 128 x 2048 f32 = 1 MB (transposed)
  proj_kernel<<<256, 256, 0, stream>>>(query, key, weight, Eq, EkT);
  attn_kernel<<<512, 512, 0, stream>>>(Eq, EkT, vT, value, out);
}

// Round 4
// 48.174 us; speedup vs baseline: 1.4221x; 1.0342x over previous
//
#include <hip/hip_runtime.h>

#define CSC 2.88539008177792681f  // 2*log2(e)

typedef float v2f __attribute__((ext_vector_type(2)));

__device__ __forceinline__ float fast_exp2(float x) {
  return __builtin_amdgcn_exp2f(x);
}
__device__ __forceinline__ float fast_rcp(float x) {
  return __builtin_amdgcn_rcpf(x);
}
__device__ __forceinline__ v2f vfma(v2f a, v2f b, v2f c) {
  return __builtin_elementwise_fma(a, b, c);
}
__device__ __forceinline__ v2f vsplat(float s) {
  v2f r;
  r[0] = s;
  r[1] = s;
  return r;
}
__device__ __forceinline__ float rdlane(float v, int l) {
  return __int_as_float(__builtin_amdgcn_readlane(__float_as_int(v), l));
}

// ---------------- projection (unchanged from round 3) ----------------
__global__ __launch_bounds__(256) void proj_kernel(
    const float* __restrict__ query, const float* __restrict__ key,
    const float* __restrict__ weight, float* __restrict__ Eq,
    float* __restrict__ EkT) {
  __shared__ __align__(16) float rows[16][128];
  __shared__ __align__(16) float tile[16][128];
  int blk = blockIdx.x;
  bool isK = blk >= 128;
  const float* src = isK ? key : query;
  int woff = isK ? 128 : 0;
  int row0 = (isK ? blk - 128 : blk) * 16;
  int tid = threadIdx.x;
#pragma unroll
  for (int i = 0; i < 8; ++i) {
    int f = i * 256 + tid;
    rows[f >> 7][f & 127] = src[(size_t)row0 * 128 + f];
  }
  __syncthreads();
  int e = tid & 127;
  int rh = (tid >> 7) * 8;  // wave-uniform
  float acc[8];
#pragma unroll
  for (int i = 0; i < 8; ++i) acc[i] = 0.f;
  const float4* wrow =
      reinterpret_cast<const float4*>(weight + (size_t)e * 256 + woff);
#pragma unroll 4
  for (int d4 = 0; d4 < 32; ++d4) {
    float4 wv = wrow[d4];
#pragma unroll
    for (int i = 0; i < 8; ++i) {
      float4 rv = *reinterpret_cast<const float4*>(&rows[rh + i][d4 * 4]);
      acc[i] = fmaf(rv.x, wv.x, acc[i]);
      acc[i] = fmaf(rv.y, wv.y, acc[i]);
      acc[i] = fmaf(rv.z, wv.z, acc[i]);
      acc[i] = fmaf(rv.w, wv.w, acc[i]);
    }
  }
  if (!isK) {
#pragma unroll
    for (int i = 0; i < 8; ++i)
      Eq[(size_t)(row0 + rh + i) * 128 + e] = fast_exp2(CSC * acc[i]);
  } else {
#pragma unroll
    for (int i = 0; i < 8; ++i) tile[rh + i][e] = fast_exp2(CSC * acc[i]);
    __syncthreads();
    int eo = tid >> 1;
    int rseg = (tid & 1) * 8;
    float4 v0 = make_float4(tile[rseg + 0][eo], tile[rseg + 1][eo],
                            tile[rseg + 2][eo], tile[rseg + 3][eo]);
    float4 v1 = make_float4(tile[rseg + 4][eo], tile[rseg + 5][eo],
                            tile[rseg + 6][eo], tile[rseg + 7][eo]);
    float* dst = EkT + (size_t)eo * 2048 + row0 + rseg;
    *reinterpret_cast<float4*>(dst) = v0;
    *reinterpret_cast<float4*>(dst + 4) = v1;
  }
}

// 4-way reciprocal combine over an e-quad, v2f-wide over 2 k.
// sum_e vT_e/(1+eq_e*ek_e) = num/den; all A>=1, den<=2^98, f32-safe.
__device__ __forceinline__ void quad4(const float4 eq, const float4 vt, v2f ek0,
                                      v2f ek1, v2f ek2, v2f ek3, v2f& acc) {
  v2f one = vsplat(1.f);
  v2f A0 = vfma(vsplat(eq.x), ek0, one);
  v2f A1 = vfma(vsplat(eq.y), ek1, one);
  v2f A2 = vfma(vsplat(eq.z), ek2, one);
  v2f A3 = vfma(vsplat(eq.w), ek3, one);
  v2f P01 = A0 * A1;
  v2f P23 = A2 * A3;
  v2f t01 = vfma(vsplat(vt.x), A1, vsplat(vt.y) * A0);
  v2f t23 = vfma(vsplat(vt.z), A3, vsplat(vt.w) * A2);
  v2f num = vfma(t23, P01, t01 * P23);
  v2f den = P01 * P23;
  v2f r;
  r[0] = fast_rcp(den[0]);
  r[1] = fast_rcp(den[1]);
  acc = vfma(num, r, acc);
}

// Attention: grid 256 (b = blk>>7, q0 = (blk&127)*8), 512 threads (8 waves).
// Block owns 8 q-rows and all 1024 k; thread owns 2 consecutive k x 8 q.
// EkT read exactly once per block (coalesced); Eq/vT via uniform scalar loads.
__global__ __launch_bounds__(512, 2) void attn_kernel(
    const float* __restrict__ Eq, const float* __restrict__ EkT,
    const float* __restrict__ vT, const float* __restrict__ value,
    float* __restrict__ out) {
  __shared__ __align__(16) float sc[8][1024];
  __shared__ __align__(16) v2f pout[8][8][64];
  __shared__ float denom[8];

  int tid = threadIdx.x;
  int lane = tid & 63;
  int w = tid >> 6;
  int b = blockIdx.x >> 7;
  int q0 = (blockIdx.x & 127) * 8;

  // ---- scores: thread -> k = {2*tid, 2*tid+1}, q rows q0..q0+7 ----
  {
    const float* ekp = EkT + (size_t)b * 1024 + 2 * tid;
    const float* eqbase = Eq + (size_t)(b * 1024 + q0) * 128;
    v2f acc[8];
#pragma unroll
    for (int q = 0; q < 8; ++q) acc[q] = vsplat(0.f);
    for (int e = 0; e < 128; e += 4) {
      v2f ek0 = *reinterpret_cast<const v2f*>(ekp + (size_t)(e + 0) * 2048);
      v2f ek1 = *reinterpret_cast<const v2f*>(ekp + (size_t)(e + 1) * 2048);
      v2f ek2 = *reinterpret_cast<const v2f*>(ekp + (size_t)(e + 2) * 2048);
      v2f ek3 = *reinterpret_cast<const v2f*>(ekp + (size_t)(e + 3) * 2048);
      float4 vt4 = *reinterpret_cast<const float4*>(vT + e);  // uniform -> SMEM
#pragma unroll
      for (int q = 0; q < 8; ++q) {
        float4 eq4 =
            *reinterpret_cast<const float4*>(eqbase + (size_t)q * 128 + e);
        quad4(eq4, vt4, ek0, ek1, ek2, ek3, acc[q]);
      }
    }
#pragma unroll
    for (int q = 0; q < 8; ++q)
      *reinterpret_cast<v2f*>(&sc[q][2 * tid]) = acc[q];
  }
  __syncthreads();

  // ---- softmax (no max pass; scores bounded): wave w -> row w ----
  {
    float sum = 0.f;
#pragma unroll
    for (int i = 0; i < 16; ++i) {
      int k = i * 64 + lane;
      float p = fast_exp2(-CSC * sc[w][k]);
      sc[w][k] = p;
      sum += p;
    }
#pragma unroll
    for (int off = 32; off; off >>= 1) sum += __shfl_xor(sum, off);
    if (lane == 0) denom[w] = sum;
  }
  __syncthreads();

  // ---- PV: wave w -> k in [w*128, w*128+128); lane -> v2f column; p values
  //      broadcast from registers via v_readlane (no LDS broadcast traffic) --
  {
    v2f acc[8];
#pragma unroll
    for (int q = 0; q < 8; ++q) acc[q] = vsplat(0.f);
    const v2f* vp = reinterpret_cast<const v2f*>(value) +
                    (size_t)b * 1024 * 64 + lane;
#pragma unroll
    for (int half = 0; half < 2; ++half) {
      int kb = w * 128 + half * 64;
      float pr[8];
#pragma unroll
      for (int q = 0; q < 8; ++q) pr[q] = sc[q][kb + lane];
#pragma unroll
      for (int kk = 0; kk < 64; ++kk) {
        v2f vv = vp[(size_t)(kb + kk) * 64];
#pragma unroll
        for (int q = 0; q < 8; ++q)
          acc[q] = vfma(vsplat(rdlane(pr[q], kk)), vv, acc[q]);
      }
    }
#pragma unroll
    for (int q = 0; q < 8; ++q) pout[w][q][lane] = acc[q];
  }
  __syncthreads();

  // ---- cross-wave reduce + normalize: thread -> (q = tid>>6, c = lane) ----
  {
    int q = tid >> 6;
    v2f r = pout[0][q][lane];
#pragma unroll
    for (int ww = 1; ww < 8; ++ww) r = r + pout[ww][q][lane];
    float inv = fast_rcp(denom[q]);
    r[0] *= inv;
    r[1] *= inv;
    reinterpret_cast<v2f*>(out)[(size_t)(b * 1024 + q0 + q) * 64 + lane] = r;
  }
}

extern "C" void kernel_launch(void* const* d_in, const int* in_sizes, int n_in,
                              void* d_out, int out_size, void* d_ws,
                              size_t ws_size, hipStream_t stream) {
  const float* query = (const float*)d_in[0];
  const float* key = (const float*)d_in[1];
  const float* value = (const float*)d_in[2];
  const float* vT = (const float*)d_in[3];
  const float* weight = (const float*)d_in[4];
  float* out = (float*)d_out;
  float* Eq = (float*)d_ws;      // 2048*128 f32 = 1 MB (row-major [row][e])
  float* EkT = Eq + 2048 * 128;  // 128 x 2048 f32 = 1 MB (transposed [e][col])
  proj_kernel<<<256, 256, 0, stream>>>(query, key, weight, Eq, EkT);
  attn_kernel<<<256, 512, 0, stream>>>(Eq, EkT, vT, value, out);
}